// Round 5
// baseline (402.612 us; speedup 1.0000x reference)
//
#include <hip/hip_runtime.h>

typedef __attribute__((ext_vector_type(8))) short bfrag8;          // 8 bf16 in 4 VGPRs
typedef __attribute__((ext_vector_type(4))) float facc4;           // 4 fp32 acc
typedef __attribute__((ext_vector_type(8))) unsigned short u16x8;  // 16B lane load

#define CROWS  256    // rows per scan bucket
#define SLACK  772    // per-bucket cidx padding slack (256 rows * 3 + align)
#define BPITCH (8192 + SLACK)  // fixed cidx pitch per bucket (ints, %4==0, ~2.2x expected)

static __device__ __forceinline__ float bf2f(ushort u) {
    union { unsigned int i; float f; } x;
    x.i = ((unsigned int)u) << 16;
    return x.f;
}
static __device__ __forceinline__ ushort f2bf(float f) {
    union { float f; unsigned int i; } x;
    x.f = f;
    unsigned int r = x.i + 0x7FFFu + ((x.i >> 16) & 1u);   // RNE
    return (ushort)(r >> 16);
}

// ---------------- prep: pack W -> bf16 frags, BN+bias -> PS/PH, zero deg/sentinels ----
// wp[l][4096]: idx(c2,ks,quad,m,j) = (((c2*2+ks)*4+quad)*16+m)*8+j  (bijective 12-bit)
//   holds bf16( W_l[(32ks+8quad+j)*64 + c2*16 + m] )  -> frag load = one 16B read
// pp[l][0..63]=PS, pp[l][64..127]=PH:  out = dr*sum*PS + PH  (then optional ReLU)
__global__ void k_prep(const float* __restrict__ W1, const float* __restrict__ W2,
                       const float* __restrict__ W3,
                       const float* __restrict__ b1, const float* __restrict__ g1,
                       const float* __restrict__ be1, const float* __restrict__ m1,
                       const float* __restrict__ v1,
                       const float* __restrict__ b2, const float* __restrict__ g2,
                       const float* __restrict__ be2, const float* __restrict__ m2,
                       const float* __restrict__ v2,
                       const float* __restrict__ b3,
                       ushort* __restrict__ wp, float* __restrict__ pp,
                       int* __restrict__ deg,
                       ushort* __restrict__ ta, ushort* __restrict__ tb, int N) {
    int l = blockIdx.x;
    if (l < 3) {
        const float* W = (l == 0) ? W1 : (l == 1) ? W2 : W3;
        ushort* wo = wp + l * 4096;
        for (int idx = threadIdx.x; idx < 4096; idx += blockDim.x) {
            int j = idx & 7, m = (idx >> 3) & 15, quad = (idx >> 7) & 3;
            int ks = (idx >> 9) & 1, c2 = idx >> 10;
            wo[idx] = f2bf(W[(32 * ks + 8 * quad + j) * 64 + c2 * 16 + m]);
        }
        if (threadIdx.x < 64) {
            int ch = threadIdx.x;
            float PS, PH;
            if (l == 0) {
                float sc = g1[ch] * rsqrtf(v1[ch] + 1e-5f);
                PS = sc; PH = be1[ch] - m1[ch] * sc + b1[ch] * sc;
            } else if (l == 1) {
                float sc = g2[ch] * rsqrtf(v2[ch] + 1e-5f);
                PS = sc; PH = be2[ch] - m2[ch] * sc + b2[ch] * sc;
            } else {
                PS = 1.f; PH = b3[ch];
            }
            pp[l * 128 + ch] = PS;
            pp[l * 128 + 64 + ch] = PH;
        }
    }
    if (l == 3 && threadIdx.x < 128) {
        int t = threadIdx.x;
        if (t < 64) ta[(size_t)N * 64 + t] = 0;
        else        tb[(size_t)N * 64 + (t - 64)] = 0;
    }
    int t = blockIdx.x * blockDim.x + threadIdx.x;
    int stride = gridDim.x * blockDim.x;
    for (int i = t; i < N; i += stride) deg[i] = 0;
}

// ---------------- preprocessing: deg -> bucket scan -> direct placement ----------

__global__ void k_deg(const int* __restrict__ row, int E, int* __restrict__ deg) {
    int t = blockIdx.x * blockDim.x + threadIdx.x;
    int stride = gridDim.x * blockDim.x;
    for (int e = t; e < E; e += stride) atomicAdd(&deg[row[e]], 1);
}

// per 256-row bucket: padded-window scan (fixed BPITCH base -> no global scan),
// write rptr/cur/dinv + sentinel entries (disjoint from placement region).
__global__ void k_scanB(const int* __restrict__ deg, int* __restrict__ rptr,
                        float* __restrict__ dinv, int* __restrict__ cur,
                        int* __restrict__ cidx, int N) {
    __shared__ int psum[CROWS];
    int tid = threadIdx.x;
    int b = blockIdx.x;
    int lo = b * CROWS;
    int nr = min(CROWS, N - lo);
    int d = (tid < nr) ? deg[lo + tid] : 0;
    int ep = (d + 3) & ~3;               // padded row length (multiple of 4)
    psum[tid] = ep;
    __syncthreads();
    #pragma unroll
    for (int off = 1; off < CROWS; off <<= 1) {
        int t = (tid >= off) ? psum[tid - off] : 0;
        __syncthreads();
        psum[tid] += t;
        __syncthreads();
    }
    if (tid < nr) {
        int ws = b * BPITCH + psum[tid] - ep;
        rptr[lo + tid] = ws;
        cur[lo + tid] = ws;
        dinv[lo + tid] = rsqrtf((float)(d + 1));   // +1 self-loop
        for (int j = d; j < ep; j++) cidx[ws + j] = N;   // sentinels
    }
}

__global__ void k_place(const int* __restrict__ row, const int* __restrict__ col, int E,
                        int* __restrict__ cur, int* __restrict__ cidx) {
    int t = blockIdx.x * blockDim.x + threadIdx.x;
    int stride = gridDim.x * blockDim.x;
    for (int e = t; e < E; e += stride) {
        int r = row[e];
        int p = atomicAdd(&cur[r], 1);
        cidx[p] = col[e];
    }
}

// ---------------- MFMA GEMM: T2[N,64] = dinv[n] * (H[N,64] @ W[64,64]) ----------------
// only used for layer 1 (fp32 x input); W from prepacked bf16 fragments
__global__ void k_gemm(const float* __restrict__ Hv, const ushort* __restrict__ wq,
                       const float* __restrict__ dinv,
                       ushort* __restrict__ T, int ntiles, int N) {
    int lane = threadIdx.x & 63;
    int wid = (blockIdx.x * blockDim.x + threadIdx.x) >> 6;
    int nw = (gridDim.x * blockDim.x) >> 6;
    int m = lane & 15, quad = lane >> 4;

    bfrag8 bf[2][4];   // all of W in B-frags, one 16B load each
    #pragma unroll
    for (int s = 0; s < 2; s++)
        #pragma unroll
        for (int c = 0; c < 4; c++)
            bf[s][c] = *(const bfrag8*)(wq +
                (size_t)((((c * 2 + s) * 4 + quad) * 16 + m) * 8));

    for (int t = wid; t < ntiles; t += nw) {
        int nodeA = t * 16 + m;
        if (nodeA >= N) nodeA = N - 1;
        bfrag8 a0, a1;
        const float* arow = Hv + (size_t)nodeA * 64;
        #pragma unroll
        for (int s = 0; s < 2; s++) {
            float4 u0 = *(const float4*)(arow + s * 32 + quad * 8);
            float4 u1 = *(const float4*)(arow + s * 32 + quad * 8 + 4);
            bfrag8 f;
            f[0] = (short)f2bf(u0.x); f[1] = (short)f2bf(u0.y);
            f[2] = (short)f2bf(u0.z); f[3] = (short)f2bf(u0.w);
            f[4] = (short)f2bf(u1.x); f[5] = (short)f2bf(u1.y);
            f[6] = (short)f2bf(u1.z); f[7] = (short)f2bf(u1.w);
            if (s == 0) a0 = f; else a1 = f;
        }
        facc4 acc[4];
        #pragma unroll
        for (int c = 0; c < 4; c++) { acc[c][0]=0.f; acc[c][1]=0.f; acc[c][2]=0.f; acc[c][3]=0.f; }
        #pragma unroll
        for (int c = 0; c < 4; c++) {
            acc[c] = __builtin_amdgcn_mfma_f32_16x16x32_bf16(a0, bf[0][c], acc[c], 0, 0, 0);
            acc[c] = __builtin_amdgcn_mfma_f32_16x16x32_bf16(a1, bf[1][c], acc[c], 0, 0, 0);
        }
        #pragma unroll
        for (int c = 0; c < 4; c++)
            #pragma unroll
            for (int r = 0; r < 4; r++) {
                int node = t * 16 + quad * 4 + r;
                if (node < N)
                    T[(size_t)node * 64 + c * 16 + m] = f2bf(dinv[node] * acc[c][r]);
            }
    }
}

// ---------------- fused propagate + (BN+bias via PS/PH) + ReLU (+ next GEMM) ------
// Block = 4 waves = 32 contiguous rows. Index loads software-pipelined one packet
// ahead (affine addresses, independent of gather results). Self-row load hoisted.
template <bool FUSE>
__global__ void __launch_bounds__(256, 6)
k_aggf(const ushort* __restrict__ T2, const int* __restrict__ rptr,
       const int* __restrict__ deg, const float* __restrict__ dinv,
       const int* __restrict__ cidx,
       const float* __restrict__ pp, int relu,
       const ushort* __restrict__ wq,
       float* __restrict__ outf, ushort* __restrict__ Tn, int N) {
    __shared__ ushort lds_h[32][72];   // +8 shorts pad: 2-way max bank alias (free)

    int tid = threadIdx.x;
    int lane = tid & 63;
    int wl = tid >> 6;        // wave in block, 0..3
    int grp = lane >> 3;      // which of 8 rows in this wave
    int s = lane & 7;         // channel slice: s*8 .. s*8+7
    int loc = wl * 8 + grp;   // block-local row 0..31
    int r = blockIdx.x * 32 + loc;
    bool rv = (r < N);
    int rs = rv ? r : N;      // sentinel row for inactive lanes (zeros)

    int start = rv ? rptr[r] : 0;
    int ep = rv ? ((deg[r] + 3) & ~3) : 0;
    // self-row load issued before the gather loop (long overlap window)
    u16x8 sf = *(const u16x8*)(T2 + (size_t)rs * 64 + s * 8);
    float dr = rv ? dinv[r] : 0.f;

    float a[8];
    #pragma unroll
    for (int k = 0; k < 8; k++) a[k] = 0.f;

    int i = 0;
    bool have8 = (8 <= ep);
    int4 c4, d4;
    if (have8) {
        c4 = *(const int4*)(cidx + start);
        d4 = *(const int4*)(cidx + start + 4);
    }
    while (have8) {
        int ni = i + 8;
        bool nhave = (ni + 8 <= ep);
        int4 nc4, nd4;
        if (nhave) {                      // prefetch next packet's indices
            nc4 = *(const int4*)(cidx + start + ni);
            nd4 = *(const int4*)(cidx + start + ni + 4);
        }
        u16x8 t0 = *(const u16x8*)(T2 + (size_t)c4.x * 64 + s * 8);
        u16x8 t1 = *(const u16x8*)(T2 + (size_t)c4.y * 64 + s * 8);
        u16x8 t2 = *(const u16x8*)(T2 + (size_t)c4.z * 64 + s * 8);
        u16x8 t3 = *(const u16x8*)(T2 + (size_t)c4.w * 64 + s * 8);
        u16x8 t4 = *(const u16x8*)(T2 + (size_t)d4.x * 64 + s * 8);
        u16x8 t5 = *(const u16x8*)(T2 + (size_t)d4.y * 64 + s * 8);
        u16x8 t6 = *(const u16x8*)(T2 + (size_t)d4.z * 64 + s * 8);
        u16x8 t7 = *(const u16x8*)(T2 + (size_t)d4.w * 64 + s * 8);
        #pragma unroll
        for (int k = 0; k < 8; k++)
            a[k] += ((bf2f(t0[k]) + bf2f(t1[k])) + (bf2f(t2[k]) + bf2f(t3[k]))) +
                    ((bf2f(t4[k]) + bf2f(t5[k])) + (bf2f(t6[k]) + bf2f(t7[k])));
        c4 = nc4; d4 = nd4; i = ni; have8 = nhave;
    }
    if (i < ep) {                            // tail packet of 4
        int4 e4 = *(const int4*)(cidx + start + i);
        u16x8 t0 = *(const u16x8*)(T2 + (size_t)e4.x * 64 + s * 8);
        u16x8 t1 = *(const u16x8*)(T2 + (size_t)e4.y * 64 + s * 8);
        u16x8 t2 = *(const u16x8*)(T2 + (size_t)e4.z * 64 + s * 8);
        u16x8 t3 = *(const u16x8*)(T2 + (size_t)e4.w * 64 + s * 8);
        #pragma unroll
        for (int k = 0; k < 8; k++)
            a[k] += (bf2f(t0[k]) + bf2f(t1[k])) + (bf2f(t2[k]) + bf2f(t3[k]));
    }

    // epilogue params loaded after the gather loop (short live range)
    float4 ps0 = *(const float4*)(pp + s * 8);
    float4 ps1 = *(const float4*)(pp + s * 8 + 4);
    float4 ph0 = *(const float4*)(pp + 64 + s * 8);
    float4 ph1 = *(const float4*)(pp + 64 + s * 8 + 4);
    float PS[8] = {ps0.x, ps0.y, ps0.z, ps0.w, ps1.x, ps1.y, ps1.z, ps1.w};
    float PH[8] = {ph0.x, ph0.y, ph0.z, ph0.w, ph1.x, ph1.y, ph1.z, ph1.w};

    float v[8];
    #pragma unroll
    for (int k = 0; k < 8; k++) v[k] = 0.f;
    if (rv) {
        #pragma unroll
        for (int k = 0; k < 8; k++) {
            v[k] = dr * (a[k] + bf2f(sf[k])) * PS[k] + PH[k];
            if (relu) v[k] = fmaxf(v[k], 0.f);
        }
        if (outf) {
            *(float4*)(outf + (size_t)r * 64 + s * 8) = make_float4(v[0], v[1], v[2], v[3]);
            *(float4*)(outf + (size_t)r * 64 + s * 8 + 4) = make_float4(v[4], v[5], v[6], v[7]);
        }
    }

    if constexpr (FUSE) {
        // stage activation tile (bf16) into LDS
        u16x8 hv;
        #pragma unroll
        for (int k = 0; k < 8; k++) hv[k] = rv ? f2bf(v[k]) : (ushort)0;
        *(u16x8*)&lds_h[loc][s * 8] = hv;

        // prepacked Wn fragments: one 16B load each
        int m = lane & 15, quad = lane >> 4;
        int rtile = wl >> 1, chalf = wl & 1;   // wave -> (16-row tile, 32-col half)
        bfrag8 bw[2][2];
        #pragma unroll
        for (int ks = 0; ks < 2; ks++)
            #pragma unroll
            for (int c = 0; c < 2; c++)
                bw[ks][c] = *(const bfrag8*)(wq +
                    (size_t)(((((chalf * 2 + c) * 2 + ks) * 4 + quad) * 16 + m) * 8));
        __syncthreads();

        bfrag8 a0 = *(const bfrag8*)&lds_h[rtile * 16 + m][quad * 8];
        bfrag8 a1 = *(const bfrag8*)&lds_h[rtile * 16 + m][32 + quad * 8];
        facc4 acc[2];
        #pragma unroll
        for (int c = 0; c < 2; c++) { acc[c][0]=0.f; acc[c][1]=0.f; acc[c][2]=0.f; acc[c][3]=0.f; }
        #pragma unroll
        for (int c = 0; c < 2; c++) {
            acc[c] = __builtin_amdgcn_mfma_f32_16x16x32_bf16(a0, bw[0][c], acc[c], 0, 0, 0);
            acc[c] = __builtin_amdgcn_mfma_f32_16x16x32_bf16(a1, bw[1][c], acc[c], 0, 0, 0);
        }
        int nodeBase = blockIdx.x * 32 + rtile * 16;
        #pragma unroll
        for (int c = 0; c < 2; c++)
            #pragma unroll
            for (int rr = 0; rr < 4; rr++) {
                int node = nodeBase + quad * 4 + rr;
                if (node < N)
                    Tn[(size_t)node * 64 + (chalf * 2 + c) * 16 + m] =
                        f2bf(dinv[node] * acc[c][rr]);
            }
    }
}

// ---------------- launcher ----------------

extern "C" void kernel_launch(void* const* d_in, const int* in_sizes, int n_in,
                              void* d_out, int out_size, void* d_ws, size_t ws_size,
                              hipStream_t stream) {
    const float* x  = (const float*)d_in[0];
    const int*   ei = (const int*)d_in[1];
    const float *W1 = (const float*)d_in[2],  *b1 = (const float*)d_in[3];
    const float *g1 = (const float*)d_in[4],  *be1= (const float*)d_in[5];
    const float *m1 = (const float*)d_in[6],  *v1 = (const float*)d_in[7];
    const float *W2 = (const float*)d_in[8],  *b2 = (const float*)d_in[9];
    const float *g2 = (const float*)d_in[10], *be2= (const float*)d_in[11];
    const float *m2 = (const float*)d_in[12], *v2 = (const float*)d_in[13];
    const float *W3 = (const float*)d_in[14], *b3 = (const float*)d_in[15];

    int N = in_sizes[0] / 64;
    int E = in_sizes[1] / 2;
    const int* row = ei;
    const int* col = ei + E;
    int ncb = (N + CROWS - 1) / CROWS;

    char* p = (char*)d_ws;
    auto take = [&](size_t b) -> char* {
        char* q = p;
        p += (b + 255) & ~(size_t)255;
        return q;
    };
    int*    rptr  = (int*)   take((size_t)N * 4);
    int*    deg   = (int*)   take((size_t)N * 4);
    int*    cur   = (int*)   take((size_t)N * 4);
    float*  dinv  = (float*) take((size_t)N * 4);
    ushort* wp    = (ushort*)take((size_t)3 * 4096 * 2);
    float*  pp    = (float*) take((size_t)3 * 128 * 4);
    int*    cidx  = (int*)   take((size_t)ncb * BPITCH * 4 + 1024);
    ushort* ta    = (ushort*)take((size_t)(N + 1) * 64 * 2);   // +1 sentinel row
    ushort* tb    = (ushort*)take((size_t)(N + 1) * 64 * 2);   // double buffer

    const int TB = 256;
    const int TBP = 1024;
    int GE = (E + TBP * 4 - 1) / (TBP * 4);    // 4 edges/thread

    k_prep <<<32, TB, 0, stream>>>(W1, W2, W3, b1, g1, be1, m1, v1,
                                   b2, g2, be2, m2, v2, b3, wp, pp, deg, ta, tb, N);
    k_deg  <<<GE, TBP, 0, stream>>>(row, E, deg);
    k_scanB<<<ncb, CROWS, 0, stream>>>(deg, rptr, dinv, cur, cidx, N);
    k_place<<<GE, TBP, 0, stream>>>(row, col, E, cur, cidx);

    float* outp = (float*)d_out;   // [0, N*64): embeddings fp32; [N*64, 2N*64): preds
    int ntiles = (N + 15) >> 4;
    int GG = (ntiles + 3) / 4;                 // 1 tile per wave
    int GA = (N + 31) / 32;                    // 32 rows per block

    // layer 1 GEMM (fp32 x input) -> ta
    k_gemm<<<GG, TB, 0, stream>>>(x, wp, dinv, ta, ntiles, N);
    // layer 1 agg + fused GEMM W2 -> tb
    k_aggf<true><<<GA, TB, 0, stream>>>(ta, rptr, deg, dinv, cidx, pp, 1,
                                        wp + 4096, (float*)nullptr, tb, N);
    // layer 2 agg (embeddings fp32 out) + fused GEMM W3 -> ta
    k_aggf<true><<<GA, TB, 0, stream>>>(tb, rptr, deg, dinv, cidx, pp + 128, 1,
                                        wp + 8192, outp, ta, N);
    // layer 3 agg -> predictions
    k_aggf<false><<<GA, TB, 0, stream>>>(ta, rptr, deg, dinv, cidx, pp + 256, 0,
                                         (const ushort*)nullptr,
                                         outp + (size_t)N * 64, (ushort*)nullptr, N);
}

// Round 6
// 258.893 us; speedup vs baseline: 1.5551x; 1.5551x over previous
//
#include <hip/hip_runtime.h>

typedef __attribute__((ext_vector_type(8))) short bfrag8;          // 8 bf16 in 4 VGPRs
typedef __attribute__((ext_vector_type(4))) float facc4;           // 4 fp32 acc
typedef __attribute__((ext_vector_type(8))) unsigned short u16x8;  // 16B lane load

#define CROWS  256    // rows per coarse bucket (rl fits 8 bits)
#define NCBMAX 512    // max coarse buckets (N <= 131072; col fits 17 bits)
#define CAP    8192   // bkt region capacity per bucket (~2x expected 4081)
#define CHUNK  4096   // edges per k_part block
#define SLACK  772    // per-bucket cidx padding slack (256 rows * 3 + align)
#define BPITCH (CAP + SLACK)   // fixed cidx pitch per bucket (ints, %4==0)

static __device__ __forceinline__ float bf2f(ushort u) {
    union { unsigned int i; float f; } x;
    x.i = ((unsigned int)u) << 16;
    return x.f;
}
static __device__ __forceinline__ ushort f2bf(float f) {
    union { float f; unsigned int i; } x;
    x.f = f;
    unsigned int r = x.i + 0x7FFFu + ((x.i >> 16) & 1u);   // RNE
    return (ushort)(r >> 16);
}

// ---------------- prep: pack W -> bf16 fragment layout, fuse BN+bias -> PS/PH ----
// wp[l][4096]: idx(c2,ks,quad,m,j) = (((c2*2+ks)*4+quad)*16+m)*8+j  (bijective 12b)
//   holds bf16( W_l[(32ks+8quad+j)*64 + c2*16 + m] )  -> frag load = one 16B read
// pp[l][0..63]=PS, pp[l][64..127]=PH:  out = dr*sum*PS + PH  (then optional ReLU)
__global__ void k_prep(const float* __restrict__ W1, const float* __restrict__ W2,
                       const float* __restrict__ W3,
                       const float* __restrict__ b1, const float* __restrict__ g1,
                       const float* __restrict__ be1, const float* __restrict__ m1,
                       const float* __restrict__ v1,
                       const float* __restrict__ b2, const float* __restrict__ g2,
                       const float* __restrict__ be2, const float* __restrict__ m2,
                       const float* __restrict__ v2,
                       const float* __restrict__ b3,
                       ushort* __restrict__ wp, float* __restrict__ pp) {
    int l = blockIdx.x;
    const float* W = (l == 0) ? W1 : (l == 1) ? W2 : W3;
    ushort* wo = wp + l * 4096;
    for (int idx = threadIdx.x; idx < 4096; idx += blockDim.x) {
        int j = idx & 7, m = (idx >> 3) & 15, quad = (idx >> 7) & 3;
        int ks = (idx >> 9) & 1, c2 = idx >> 10;
        wo[idx] = f2bf(W[(32 * ks + 8 * quad + j) * 64 + c2 * 16 + m]);
    }
    if (threadIdx.x < 64) {
        int ch = threadIdx.x;
        float PS, PH;
        if (l == 0) {
            float sc = g1[ch] * rsqrtf(v1[ch] + 1e-5f);
            PS = sc; PH = be1[ch] - m1[ch] * sc + b1[ch] * sc;
        } else if (l == 1) {
            float sc = g2[ch] * rsqrtf(v2[ch] + 1e-5f);
            PS = sc; PH = be2[ch] - m2[ch] * sc + b2[ch] * sc;
        } else {
            PS = 1.f; PH = b3[ch];
        }
        pp[l * 128 + ch] = PS;
        pp[l * 128 + 64 + ch] = PH;
    }
}

// ---------------- preprocessing: 2-phase partition, no global random atomics ----

__global__ void k_cinit(int* __restrict__ ccur, int ncb,
                        ushort* __restrict__ ta, ushort* __restrict__ tb, int N) {
    int b = blockIdx.x * blockDim.x + threadIdx.x;
    if (b < ncb) ccur[b] = b * CAP;
    if (blockIdx.x == 0 && threadIdx.x < 64) {
        ta[(size_t)N * 64 + threadIdx.x] = 0;
        tb[(size_t)N * 64 + threadIdx.x] = 0;
    }
}

// launched with 1024 threads (4 edges/thread) for latency hiding
__global__ void k_part(const int* __restrict__ row, const int* __restrict__ col, int E,
                       int* __restrict__ ccur, int* __restrict__ bkt, int ncb) {
    __shared__ int recs[CHUNK];          // packed (rl<<17|col)
    __shared__ unsigned short cbl[CHUNK];
    __shared__ int hist[NCBMAX], lbase[NCBMAX], loff[NCBMAX];
    int tid = threadIdx.x;
    int chunk0 = blockIdx.x * CHUNK;
    for (int i = tid; i < ncb; i += blockDim.x) hist[i] = 0;
    __syncthreads();
    for (int j = tid; j < CHUNK; j += blockDim.x) {
        int e = chunk0 + j;
        if (e < E) {
            int r = row[e];
            int cb = r >> 8;
            recs[j] = ((r & (CROWS - 1)) << 17) | col[e];
            cbl[j] = (unsigned short)cb;
            atomicAdd(&hist[cb], 1);
        } else cbl[j] = 0xFFFF;
    }
    __syncthreads();
    for (int i = tid; i < ncb; i += blockDim.x) {
        int h = hist[i];
        lbase[i] = h ? atomicAdd(&ccur[i], h) : 0;
        loff[i] = 0;
    }
    __syncthreads();
    for (int j = tid; j < CHUNK; j += blockDim.x) {
        unsigned short cb = cbl[j];
        if (cb != 0xFFFF) {
            int p = lbase[cb] + atomicAdd(&loff[cb], 1);
            if (p < (cb + 1) * CAP) bkt[p] = recs[j];   // overflow guard (never hits)
        }
    }
}

// per bucket: row hist -> deg/dinv, padded-window scan -> rptr (4-aligned),
// LDS-cursor placement, sentinel fill. Zero global atomics. Fixed bucket pitch.
// Launched with 1024 threads. (single hist: tile segmentation removed — R4 showed
// within-row tile order doesn't change FETCH_SIZE)
__global__ void k_build(const int* __restrict__ bkt, const int* __restrict__ ccur,
                        int* __restrict__ rptr, int* __restrict__ deg,
                        float* __restrict__ dinv, int* __restrict__ cidx, int N) {
    __shared__ int hist[CROWS], wstart[CROWS], cur[CROWS], psum[CROWS];
    int tid = threadIdx.x;
    int b = blockIdx.x;
    int lo = b * CROWS;
    int nr = min(CROWS, N - lo);
    int in0 = b * CAP;
    int cntE = min(ccur[b] - in0, CAP);
    int out0 = b * BPITCH;               // fixed-pitch bucket base (16B aligned)

    if (tid < CROWS) hist[tid] = 0;
    __syncthreads();
    for (int i = tid; i < cntE; i += blockDim.x)
        atomicAdd(&hist[bkt[in0 + i] >> 17], 1);
    __syncthreads();
    int d = 0, ep = 0;
    if (tid < CROWS) {
        d = hist[tid];
        ep = (d + 3) & ~3;               // padded row length (multiple of 4)
        psum[tid] = ep;
    }
    __syncthreads();
    #pragma unroll
    for (int off = 1; off < CROWS; off <<= 1) {
        int t = (tid >= off && tid < CROWS) ? psum[tid - off] : 0;
        __syncthreads();
        if (tid < CROWS) psum[tid] += t;
        __syncthreads();
    }
    if (tid < CROWS) {
        int ws = out0 + psum[tid] - ep;
        wstart[tid] = ws;
        cur[tid] = ws;
        if (tid < nr) {
            rptr[lo + tid] = ws;
            deg[lo + tid] = d;
            dinv[lo + tid] = rsqrtf((float)(d + 1));   // +1 self-loop
        }
    }
    __syncthreads();
    for (int i = tid; i < cntE; i += blockDim.x) {
        int v = bkt[in0 + i];
        int p = atomicAdd(&cur[v >> 17], 1);
        cidx[p] = v & 0x1FFFF;
    }
    __syncthreads();
    if (tid < nr) {
        int dd = hist[tid];
        int epp = (dd + 3) & ~3;
        for (int j = dd; j < epp; j++) cidx[wstart[tid] + j] = N;   // sentinels
    }
}

// ---------------- MFMA GEMM: T2[N,64] = dinv[n] * (H[N,64] @ W[64,64]) ----------------
// only used for layer 1 (fp32 x input); W from prepacked bf16 fragments
__global__ void k_gemm(const float* __restrict__ Hv, const ushort* __restrict__ wq,
                       const float* __restrict__ dinv,
                       ushort* __restrict__ T, int ntiles, int N) {
    int lane = threadIdx.x & 63;
    int wid = (blockIdx.x * blockDim.x + threadIdx.x) >> 6;
    int nw = (gridDim.x * blockDim.x) >> 6;
    int m = lane & 15, quad = lane >> 4;

    bfrag8 bf[2][4];   // all of W in B-frags, one 16B load each
    #pragma unroll
    for (int s = 0; s < 2; s++)
        #pragma unroll
        for (int c = 0; c < 4; c++)
            bf[s][c] = *(const bfrag8*)(wq +
                (size_t)((((c * 2 + s) * 4 + quad) * 16 + m) * 8));

    for (int t = wid; t < ntiles; t += nw) {
        int nodeA = t * 16 + m;
        if (nodeA >= N) nodeA = N - 1;
        bfrag8 a0, a1;
        const float* arow = Hv + (size_t)nodeA * 64;
        #pragma unroll
        for (int s = 0; s < 2; s++) {
            float4 u0 = *(const float4*)(arow + s * 32 + quad * 8);
            float4 u1 = *(const float4*)(arow + s * 32 + quad * 8 + 4);
            bfrag8 f;
            f[0] = (short)f2bf(u0.x); f[1] = (short)f2bf(u0.y);
            f[2] = (short)f2bf(u0.z); f[3] = (short)f2bf(u0.w);
            f[4] = (short)f2bf(u1.x); f[5] = (short)f2bf(u1.y);
            f[6] = (short)f2bf(u1.z); f[7] = (short)f2bf(u1.w);
            if (s == 0) a0 = f; else a1 = f;
        }
        facc4 acc[4];
        #pragma unroll
        for (int c = 0; c < 4; c++) { acc[c][0]=0.f; acc[c][1]=0.f; acc[c][2]=0.f; acc[c][3]=0.f; }
        #pragma unroll
        for (int c = 0; c < 4; c++) {
            acc[c] = __builtin_amdgcn_mfma_f32_16x16x32_bf16(a0, bf[0][c], acc[c], 0, 0, 0);
            acc[c] = __builtin_amdgcn_mfma_f32_16x16x32_bf16(a1, bf[1][c], acc[c], 0, 0, 0);
        }
        #pragma unroll
        for (int c = 0; c < 4; c++)
            #pragma unroll
            for (int r = 0; r < 4; r++) {
                int node = t * 16 + quad * 4 + r;
                if (node < N)
                    T[(size_t)node * 64 + c * 16 + m] = f2bf(dinv[node] * acc[c][r]);
            }
    }
}

// ---------------- fused propagate + (BN+bias via PS/PH) + ReLU (+ next GEMM) ------
// Block = 4 waves = 32 contiguous rows. Index loads software-pipelined one packet
// ahead (affine addresses, independent of gather results). Self-row load hoisted.
template <bool FUSE>
__global__ void __launch_bounds__(256, 6)
k_aggf(const ushort* __restrict__ T2, const int* __restrict__ rptr,
       const int* __restrict__ deg, const float* __restrict__ dinv,
       const int* __restrict__ cidx,
       const float* __restrict__ pp, int relu,
       const ushort* __restrict__ wq,
       float* __restrict__ outf, ushort* __restrict__ Tn, int N) {
    __shared__ ushort lds_h[32][72];   // +8 shorts pad: 2-way max bank alias (free)

    int tid = threadIdx.x;
    int lane = tid & 63;
    int wl = tid >> 6;        // wave in block, 0..3
    int grp = lane >> 3;      // which of 8 rows in this wave
    int s = lane & 7;         // channel slice: s*8 .. s*8+7
    int loc = wl * 8 + grp;   // block-local row 0..31
    int r = blockIdx.x * 32 + loc;
    bool rv = (r < N);
    int rs = rv ? r : N;      // sentinel row for inactive lanes (zeros)

    int start = rv ? rptr[r] : 0;
    int ep = rv ? ((deg[r] + 3) & ~3) : 0;
    // self-row load issued before the gather loop (long overlap window)
    u16x8 sf = *(const u16x8*)(T2 + (size_t)rs * 64 + s * 8);
    float dr = rv ? dinv[r] : 0.f;

    float a[8];
    #pragma unroll
    for (int k = 0; k < 8; k++) a[k] = 0.f;

    int i = 0;
    bool have8 = (8 <= ep);
    int4 c4, d4;
    if (have8) {
        c4 = *(const int4*)(cidx + start);
        d4 = *(const int4*)(cidx + start + 4);
    }
    while (have8) {
        int ni = i + 8;
        bool nhave = (ni + 8 <= ep);
        int4 nc4, nd4;
        if (nhave) {                      // prefetch next packet's indices
            nc4 = *(const int4*)(cidx + start + ni);
            nd4 = *(const int4*)(cidx + start + ni + 4);
        }
        u16x8 t0 = *(const u16x8*)(T2 + (size_t)c4.x * 64 + s * 8);
        u16x8 t1 = *(const u16x8*)(T2 + (size_t)c4.y * 64 + s * 8);
        u16x8 t2 = *(const u16x8*)(T2 + (size_t)c4.z * 64 + s * 8);
        u16x8 t3 = *(const u16x8*)(T2 + (size_t)c4.w * 64 + s * 8);
        u16x8 t4 = *(const u16x8*)(T2 + (size_t)d4.x * 64 + s * 8);
        u16x8 t5 = *(const u16x8*)(T2 + (size_t)d4.y * 64 + s * 8);
        u16x8 t6 = *(const u16x8*)(T2 + (size_t)d4.z * 64 + s * 8);
        u16x8 t7 = *(const u16x8*)(T2 + (size_t)d4.w * 64 + s * 8);
        #pragma unroll
        for (int k = 0; k < 8; k++)
            a[k] += ((bf2f(t0[k]) + bf2f(t1[k])) + (bf2f(t2[k]) + bf2f(t3[k]))) +
                    ((bf2f(t4[k]) + bf2f(t5[k])) + (bf2f(t6[k]) + bf2f(t7[k])));
        c4 = nc4; d4 = nd4; i = ni; have8 = nhave;
    }
    if (i < ep) {                            // tail packet of 4
        int4 e4 = *(const int4*)(cidx + start + i);
        u16x8 t0 = *(const u16x8*)(T2 + (size_t)e4.x * 64 + s * 8);
        u16x8 t1 = *(const u16x8*)(T2 + (size_t)e4.y * 64 + s * 8);
        u16x8 t2 = *(const u16x8*)(T2 + (size_t)e4.z * 64 + s * 8);
        u16x8 t3 = *(const u16x8*)(T2 + (size_t)e4.w * 64 + s * 8);
        #pragma unroll
        for (int k = 0; k < 8; k++)
            a[k] += (bf2f(t0[k]) + bf2f(t1[k])) + (bf2f(t2[k]) + bf2f(t3[k]));
    }

    // epilogue params loaded after the gather loop (short live range)
    float4 ps0 = *(const float4*)(pp + s * 8);
    float4 ps1 = *(const float4*)(pp + s * 8 + 4);
    float4 ph0 = *(const float4*)(pp + 64 + s * 8);
    float4 ph1 = *(const float4*)(pp + 64 + s * 8 + 4);
    float PS[8] = {ps0.x, ps0.y, ps0.z, ps0.w, ps1.x, ps1.y, ps1.z, ps1.w};
    float PH[8] = {ph0.x, ph0.y, ph0.z, ph0.w, ph1.x, ph1.y, ph1.z, ph1.w};

    float v[8];
    #pragma unroll
    for (int k = 0; k < 8; k++) v[k] = 0.f;
    if (rv) {
        #pragma unroll
        for (int k = 0; k < 8; k++) {
            v[k] = dr * (a[k] + bf2f(sf[k])) * PS[k] + PH[k];
            if (relu) v[k] = fmaxf(v[k], 0.f);
        }
        if (outf) {
            *(float4*)(outf + (size_t)r * 64 + s * 8) = make_float4(v[0], v[1], v[2], v[3]);
            *(float4*)(outf + (size_t)r * 64 + s * 8 + 4) = make_float4(v[4], v[5], v[6], v[7]);
        }
    }

    if constexpr (FUSE) {
        // stage activation tile (bf16) into LDS
        u16x8 hv;
        #pragma unroll
        for (int k = 0; k < 8; k++) hv[k] = rv ? f2bf(v[k]) : (ushort)0;
        *(u16x8*)&lds_h[loc][s * 8] = hv;

        // prepacked Wn fragments: one 16B load each
        int m = lane & 15, quad = lane >> 4;
        int rtile = wl >> 1, chalf = wl & 1;   // wave -> (16-row tile, 32-col half)
        bfrag8 bw[2][2];
        #pragma unroll
        for (int ks = 0; ks < 2; ks++)
            #pragma unroll
            for (int c = 0; c < 2; c++)
                bw[ks][c] = *(const bfrag8*)(wq +
                    (size_t)(((((chalf * 2 + c) * 2 + ks) * 4 + quad) * 16 + m) * 8));
        __syncthreads();

        bfrag8 a0 = *(const bfrag8*)&lds_h[rtile * 16 + m][quad * 8];
        bfrag8 a1 = *(const bfrag8*)&lds_h[rtile * 16 + m][32 + quad * 8];
        facc4 acc[2];
        #pragma unroll
        for (int c = 0; c < 2; c++) { acc[c][0]=0.f; acc[c][1]=0.f; acc[c][2]=0.f; acc[c][3]=0.f; }
        #pragma unroll
        for (int c = 0; c < 2; c++) {
            acc[c] = __builtin_amdgcn_mfma_f32_16x16x32_bf16(a0, bw[0][c], acc[c], 0, 0, 0);
            acc[c] = __builtin_amdgcn_mfma_f32_16x16x32_bf16(a1, bw[1][c], acc[c], 0, 0, 0);
        }
        int nodeBase = blockIdx.x * 32 + rtile * 16;
        #pragma unroll
        for (int c = 0; c < 2; c++)
            #pragma unroll
            for (int rr = 0; rr < 4; rr++) {
                int node = nodeBase + quad * 4 + rr;
                if (node < N)
                    Tn[(size_t)node * 64 + (chalf * 2 + c) * 16 + m] =
                        f2bf(dinv[node] * acc[c][rr]);
            }
    }
}

// ---------------- launcher ----------------

extern "C" void kernel_launch(void* const* d_in, const int* in_sizes, int n_in,
                              void* d_out, int out_size, void* d_ws, size_t ws_size,
                              hipStream_t stream) {
    const float* x  = (const float*)d_in[0];
    const int*   ei = (const int*)d_in[1];
    const float *W1 = (const float*)d_in[2],  *b1 = (const float*)d_in[3];
    const float *g1 = (const float*)d_in[4],  *be1= (const float*)d_in[5];
    const float *m1 = (const float*)d_in[6],  *v1 = (const float*)d_in[7];
    const float *W2 = (const float*)d_in[8],  *b2 = (const float*)d_in[9];
    const float *g2 = (const float*)d_in[10], *be2= (const float*)d_in[11];
    const float *m2 = (const float*)d_in[12], *v2 = (const float*)d_in[13];
    const float *W3 = (const float*)d_in[14], *b3 = (const float*)d_in[15];

    int N = in_sizes[0] / 64;
    int E = in_sizes[1] / 2;
    const int* row = ei;
    const int* col = ei + E;
    int ncb = (N + CROWS - 1) / CROWS;

    char* p = (char*)d_ws;
    auto take = [&](size_t b) -> char* {
        char* q = p;
        p += (b + 255) & ~(size_t)255;
        return q;
    };
    int*    ccur  = (int*)   take((size_t)ncb * 4);
    int*    rptr  = (int*)   take((size_t)N * 4);
    int*    deg   = (int*)   take((size_t)N * 4);
    float*  dinv  = (float*) take((size_t)N * 4);
    ushort* wp    = (ushort*)take((size_t)3 * 4096 * 2);
    float*  pp    = (float*) take((size_t)3 * 128 * 4);
    int*    bkt   = (int*)   take((size_t)ncb * CAP * 4);
    int*    cidx  = (int*)   take((size_t)ncb * BPITCH * 4 + 1024);
    ushort* ta    = (ushort*)take((size_t)(N + 1) * 64 * 2);   // +1 sentinel row
    ushort* tb    = (ushort*)take((size_t)(N + 1) * 64 * 2);   // double buffer

    const int TB = 256;
    const int TBP = 1024;                      // wide blocks for latency-bound preprocessing
    int nchunks = (E + CHUNK - 1) / CHUNK;
    k_prep <<<3, TB, 0, stream>>>(W1, W2, W3, b1, g1, be1, m1, v1,
                                  b2, g2, be2, m2, v2, b3, wp, pp);
    k_cinit<<<(ncb + TB - 1) / TB, TB, 0, stream>>>(ccur, ncb, ta, tb, N);
    k_part <<<nchunks, TBP, 0, stream>>>(row, col, E, ccur, bkt, ncb);
    k_build<<<ncb, TBP, 0, stream>>>(bkt, ccur, rptr, deg, dinv, cidx, N);

    float* outp = (float*)d_out;   // [0, N*64): embeddings fp32; [N*64, 2N*64): preds
    int ntiles = (N + 15) >> 4;
    int GG = (ntiles + 3) / 4;                 // 1 tile per wave
    int GA = (N + 31) / 32;                    // 32 rows per block

    // layer 1 GEMM (fp32 x input) -> ta
    k_gemm<<<GG, TB, 0, stream>>>(x, wp, dinv, ta, ntiles, N);
    // layer 1 agg + fused GEMM W2 -> tb
    k_aggf<true><<<GA, TB, 0, stream>>>(ta, rptr, deg, dinv, cidx, pp, 1,
                                        wp + 4096, (float*)nullptr, tb, N);
    // layer 2 agg (embeddings fp32 out) + fused GEMM W3 -> ta
    k_aggf<true><<<GA, TB, 0, stream>>>(tb, rptr, deg, dinv, cidx, pp + 128, 1,
                                        wp + 8192, outp, ta, N);
    // layer 3 agg -> predictions
    k_aggf<false><<<GA, TB, 0, stream>>>(ta, rptr, deg, dinv, cidx, pp + 256, 0,
                                         (const ushort*)nullptr,
                                         outp + (size_t)N * 64, (ushort*)nullptr, N);
}

// Round 7
// 255.040 us; speedup vs baseline: 1.5786x; 1.0151x over previous
//
#include <hip/hip_runtime.h>

typedef __attribute__((ext_vector_type(8))) short bfrag8;          // 8 bf16 in 4 VGPRs
typedef __attribute__((ext_vector_type(4))) float facc4;           // 4 fp32 acc
typedef __attribute__((ext_vector_type(8))) unsigned short u16x8;  // 16B lane load

#define CROWS  256    // rows per coarse bucket (rl fits 8 bits)
#define NCBMAX 512    // max coarse buckets (N <= 131072; col fits 17 bits)
#define CAP    8192   // bkt region capacity per bucket (~2x expected 4081)
#define CHUNK  4096   // edges per k_part block
#define SLACK  772    // per-bucket cidx padding slack (256 rows * 3 + align)
#define BPITCH (CAP + SLACK)   // fixed cidx pitch per bucket (ints, %4==0)

static __device__ __forceinline__ float bf2f(ushort u) {
    union { unsigned int i; float f; } x;
    x.i = ((unsigned int)u) << 16;
    return x.f;
}
static __device__ __forceinline__ ushort f2bf(float f) {
    union { float f; unsigned int i; } x;
    x.f = f;
    unsigned int r = x.i + 0x7FFFu + ((x.i >> 16) & 1u);   // RNE
    return (ushort)(r >> 16);
}

// ---------------- prep: pack W -> bf16 frags, BN+bias -> PS/PH, ccur/sentinel init ----
// wp[l][4096]: idx(c2,ks,quad,m,j) = (((c2*2+ks)*4+quad)*16+m)*8+j  (bijective 12b)
//   holds bf16( W_l[(32ks+8quad+j)*64 + c2*16 + m] )  -> frag load = one 16B read
// pp[l][0..63]=PS, pp[l][64..127]=PH:  out = dr*sum*PS + PH  (then optional ReLU)
__global__ void k_prep(const float* __restrict__ W1, const float* __restrict__ W2,
                       const float* __restrict__ W3,
                       const float* __restrict__ b1, const float* __restrict__ g1,
                       const float* __restrict__ be1, const float* __restrict__ m1,
                       const float* __restrict__ v1,
                       const float* __restrict__ b2, const float* __restrict__ g2,
                       const float* __restrict__ be2, const float* __restrict__ m2,
                       const float* __restrict__ v2,
                       const float* __restrict__ b3,
                       ushort* __restrict__ wp, float* __restrict__ pp,
                       int* __restrict__ ccur, int ncb,
                       ushort* __restrict__ ta, ushort* __restrict__ tb, int N) {
    int l = blockIdx.x;
    if (l < 3) {
        const float* W = (l == 0) ? W1 : (l == 1) ? W2 : W3;
        ushort* wo = wp + l * 4096;
        for (int idx = threadIdx.x; idx < 4096; idx += blockDim.x) {
            int j = idx & 7, m = (idx >> 3) & 15, quad = (idx >> 7) & 3;
            int ks = (idx >> 9) & 1, c2 = idx >> 10;
            wo[idx] = f2bf(W[(32 * ks + 8 * quad + j) * 64 + c2 * 16 + m]);
        }
        if (threadIdx.x < 64) {
            int ch = threadIdx.x;
            float PS, PH;
            if (l == 0) {
                float sc = g1[ch] * rsqrtf(v1[ch] + 1e-5f);
                PS = sc; PH = be1[ch] - m1[ch] * sc + b1[ch] * sc;
            } else if (l == 1) {
                float sc = g2[ch] * rsqrtf(v2[ch] + 1e-5f);
                PS = sc; PH = be2[ch] - m2[ch] * sc + b2[ch] * sc;
            } else {
                PS = 1.f; PH = b3[ch];
            }
            pp[l * 128 + ch] = PS;
            pp[l * 128 + 64 + ch] = PH;
        }
    } else {   // l == 3: bucket cursor init + sentinel rows of both T2 buffers
        for (int b = threadIdx.x; b < ncb; b += blockDim.x) ccur[b] = b * CAP;
        if (threadIdx.x < 128) {
            int t = threadIdx.x;
            if (t < 64) ta[(size_t)N * 64 + t] = 0;
            else        tb[(size_t)N * 64 + (t - 64)] = 0;
        }
    }
}

// ---------------- preprocessing: 2-phase partition, no global random writes ----
// LDS counting-sort per chunk -> bucket-major coalesced bkt write-out (runs of ~10
// consecutive addresses per bucket instead of 64 scattered lines per wave).
// Launched with 1024 threads (4 edges/thread).
__global__ void k_part(const int* __restrict__ row, const int* __restrict__ col, int E,
                       int* __restrict__ ccur, int* __restrict__ bkt, int ncb) {
    __shared__ int recs[CHUNK];              // packed (rl<<17|col), load order
    __shared__ unsigned short cbl[CHUNK];    // bucket of each record
    __shared__ int recs2[CHUNK];             // bucket-major sorted records
    __shared__ int gofs[CHUNK];              // global dest of each sorted record
    __shared__ int hist[NCBMAX], lbase[NCBMAX], loff[NCBMAX], lpos[NCBMAX];
    int tid = threadIdx.x;
    int chunk0 = blockIdx.x * CHUNK;
    int cnt = min(CHUNK, E - chunk0);

    for (int i = tid; i < NCBMAX; i += blockDim.x) { hist[i] = 0; }
    __syncthreads();
    for (int j = tid; j < cnt; j += blockDim.x) {
        int r = row[chunk0 + j];
        int cb = r >> 8;
        recs[j] = ((r & (CROWS - 1)) << 17) | col[chunk0 + j];
        cbl[j] = (unsigned short)cb;
        atomicAdd(&hist[cb], 1);
    }
    __syncthreads();
    for (int i = tid; i < ncb; i += blockDim.x) {
        int h = hist[i];
        lbase[i] = h ? atomicAdd(&ccur[i], h) : 0;
        loff[i] = 0;
    }
    // inclusive scan of hist -> lpos (over NCBMAX, padded zeros beyond ncb)
    if (tid < NCBMAX) lpos[tid] = hist[tid];
    __syncthreads();
    #pragma unroll
    for (int off = 1; off < NCBMAX; off <<= 1) {
        int t = (tid < NCBMAX && tid >= off) ? lpos[tid - off] : 0;
        __syncthreads();
        if (tid < NCBMAX) lpos[tid] += t;
        __syncthreads();
    }
    // place into bucket-major LDS order + compute global dests
    for (int j = tid; j < cnt; j += blockDim.x) {
        int cb = cbl[j];
        int p = atomicAdd(&loff[cb], 1);
        int lp = lpos[cb] - hist[cb] + p;        // exclusive base + offset
        recs2[lp] = recs[j];
        int gp = lbase[cb] + p;
        gofs[lp] = (gp < (cb + 1) * CAP) ? gp : -1;   // overflow guard (never hits)
    }
    __syncthreads();
    // coalesced write-out: consecutive t -> consecutive global addresses per run
    for (int t = tid; t < cnt; t += blockDim.x) {
        int g = gofs[t];
        if (g >= 0) bkt[g] = recs2[t];
    }
}

// per bucket: row hist -> deg/dinv, padded-window scan -> rptr (4-aligned),
// LDS-cursor placement, sentinel fill. Zero global atomics. Fixed bucket pitch.
// Launched with 1024 threads.
__global__ void k_build(const int* __restrict__ bkt, const int* __restrict__ ccur,
                        int* __restrict__ rptr, int* __restrict__ deg,
                        float* __restrict__ dinv, int* __restrict__ cidx, int N) {
    __shared__ int hist[CROWS], wstart[CROWS], cur[CROWS], psum[CROWS];
    int tid = threadIdx.x;
    int b = blockIdx.x;
    int lo = b * CROWS;
    int nr = min(CROWS, N - lo);
    int in0 = b * CAP;
    int cntE = min(ccur[b] - in0, CAP);
    int out0 = b * BPITCH;               // fixed-pitch bucket base (16B aligned)

    if (tid < CROWS) hist[tid] = 0;
    __syncthreads();
    for (int i = tid; i < cntE; i += blockDim.x)
        atomicAdd(&hist[bkt[in0 + i] >> 17], 1);
    __syncthreads();
    int d = 0, ep = 0;
    if (tid < CROWS) {
        d = hist[tid];
        ep = (d + 3) & ~3;               // padded row length (multiple of 4)
        psum[tid] = ep;
    }
    __syncthreads();
    #pragma unroll
    for (int off = 1; off < CROWS; off <<= 1) {
        int t = (tid >= off && tid < CROWS) ? psum[tid - off] : 0;
        __syncthreads();
        if (tid < CROWS) psum[tid] += t;
        __syncthreads();
    }
    if (tid < CROWS) {
        int ws = out0 + psum[tid] - ep;
        wstart[tid] = ws;
        cur[tid] = ws;
        if (tid < nr) {
            rptr[lo + tid] = ws;
            deg[lo + tid] = d;
            dinv[lo + tid] = rsqrtf((float)(d + 1));   // +1 self-loop
        }
    }
    __syncthreads();
    for (int i = tid; i < cntE; i += blockDim.x) {
        int v = bkt[in0 + i];
        int p = atomicAdd(&cur[v >> 17], 1);
        cidx[p] = v & 0x1FFFF;
    }
    __syncthreads();
    if (tid < nr) {
        int dd = hist[tid];
        int epp = (dd + 3) & ~3;
        for (int j = dd; j < epp; j++) cidx[wstart[tid] + j] = N;   // sentinels
    }
}

// ---------------- MFMA GEMM: T2[N,64] = dinv[n] * (H[N,64] @ W[64,64]) ----------------
// only used for layer 1 (fp32 x input); W from prepacked bf16 fragments
__global__ void k_gemm(const float* __restrict__ Hv, const ushort* __restrict__ wq,
                       const float* __restrict__ dinv,
                       ushort* __restrict__ T, int ntiles, int N) {
    int lane = threadIdx.x & 63;
    int wid = (blockIdx.x * blockDim.x + threadIdx.x) >> 6;
    int nw = (gridDim.x * blockDim.x) >> 6;
    int m = lane & 15, quad = lane >> 4;

    bfrag8 bf[2][4];   // all of W in B-frags, one 16B load each
    #pragma unroll
    for (int s = 0; s < 2; s++)
        #pragma unroll
        for (int c = 0; c < 4; c++)
            bf[s][c] = *(const bfrag8*)(wq +
                (size_t)((((c * 2 + s) * 4 + quad) * 16 + m) * 8));

    for (int t = wid; t < ntiles; t += nw) {
        int nodeA = t * 16 + m;
        if (nodeA >= N) nodeA = N - 1;
        bfrag8 a0, a1;
        const float* arow = Hv + (size_t)nodeA * 64;
        #pragma unroll
        for (int s = 0; s < 2; s++) {
            float4 u0 = *(const float4*)(arow + s * 32 + quad * 8);
            float4 u1 = *(const float4*)(arow + s * 32 + quad * 8 + 4);
            bfrag8 f;
            f[0] = (short)f2bf(u0.x); f[1] = (short)f2bf(u0.y);
            f[2] = (short)f2bf(u0.z); f[3] = (short)f2bf(u0.w);
            f[4] = (short)f2bf(u1.x); f[5] = (short)f2bf(u1.y);
            f[6] = (short)f2bf(u1.z); f[7] = (short)f2bf(u1.w);
            if (s == 0) a0 = f; else a1 = f;
        }
        facc4 acc[4];
        #pragma unroll
        for (int c = 0; c < 4; c++) { acc[c][0]=0.f; acc[c][1]=0.f; acc[c][2]=0.f; acc[c][3]=0.f; }
        #pragma unroll
        for (int c = 0; c < 4; c++) {
            acc[c] = __builtin_amdgcn_mfma_f32_16x16x32_bf16(a0, bf[0][c], acc[c], 0, 0, 0);
            acc[c] = __builtin_amdgcn_mfma_f32_16x16x32_bf16(a1, bf[1][c], acc[c], 0, 0, 0);
        }
        #pragma unroll
        for (int c = 0; c < 4; c++)
            #pragma unroll
            for (int r = 0; r < 4; r++) {
                int node = t * 16 + quad * 4 + r;
                if (node < N)
                    T[(size_t)node * 64 + c * 16 + m] = f2bf(dinv[node] * acc[c][r]);
            }
    }
}

// ---------------- fused propagate + (BN+bias via PS/PH) + ReLU (+ next GEMM) ------
// Block = 4 waves = 32 contiguous rows. Index loads software-pipelined one packet
// ahead (affine addresses, independent of gather results). Self-row load hoisted.
template <bool FUSE>
__global__ void __launch_bounds__(256, 6)
k_aggf(const ushort* __restrict__ T2, const int* __restrict__ rptr,
       const int* __restrict__ deg, const float* __restrict__ dinv,
       const int* __restrict__ cidx,
       const float* __restrict__ pp, int relu,
       const ushort* __restrict__ wq,
       float* __restrict__ outf, ushort* __restrict__ Tn, int N) {
    __shared__ ushort lds_h[32][72];   // +8 shorts pad: 2-way max bank alias (free)

    int tid = threadIdx.x;
    int lane = tid & 63;
    int wl = tid >> 6;        // wave in block, 0..3
    int grp = lane >> 3;      // which of 8 rows in this wave
    int s = lane & 7;         // channel slice: s*8 .. s*8+7
    int loc = wl * 8 + grp;   // block-local row 0..31
    int r = blockIdx.x * 32 + loc;
    bool rv = (r < N);
    int rs = rv ? r : N;      // sentinel row for inactive lanes (zeros)

    int start = rv ? rptr[r] : 0;
    int ep = rv ? ((deg[r] + 3) & ~3) : 0;
    // self-row load issued before the gather loop (long overlap window)
    u16x8 sf = *(const u16x8*)(T2 + (size_t)rs * 64 + s * 8);
    float dr = rv ? dinv[r] : 0.f;

    float a[8];
    #pragma unroll
    for (int k = 0; k < 8; k++) a[k] = 0.f;

    int i = 0;
    bool have8 = (8 <= ep);
    int4 c4, d4;
    if (have8) {
        c4 = *(const int4*)(cidx + start);
        d4 = *(const int4*)(cidx + start + 4);
    }
    while (have8) {
        int ni = i + 8;
        bool nhave = (ni + 8 <= ep);
        int4 nc4, nd4;
        if (nhave) {                      // prefetch next packet's indices
            nc4 = *(const int4*)(cidx + start + ni);
            nd4 = *(const int4*)(cidx + start + ni + 4);
        }
        u16x8 t0 = *(const u16x8*)(T2 + (size_t)c4.x * 64 + s * 8);
        u16x8 t1 = *(const u16x8*)(T2 + (size_t)c4.y * 64 + s * 8);
        u16x8 t2 = *(const u16x8*)(T2 + (size_t)c4.z * 64 + s * 8);
        u16x8 t3 = *(const u16x8*)(T2 + (size_t)c4.w * 64 + s * 8);
        u16x8 t4 = *(const u16x8*)(T2 + (size_t)d4.x * 64 + s * 8);
        u16x8 t5 = *(const u16x8*)(T2 + (size_t)d4.y * 64 + s * 8);
        u16x8 t6 = *(const u16x8*)(T2 + (size_t)d4.z * 64 + s * 8);
        u16x8 t7 = *(const u16x8*)(T2 + (size_t)d4.w * 64 + s * 8);
        #pragma unroll
        for (int k = 0; k < 8; k++)
            a[k] += ((bf2f(t0[k]) + bf2f(t1[k])) + (bf2f(t2[k]) + bf2f(t3[k]))) +
                    ((bf2f(t4[k]) + bf2f(t5[k])) + (bf2f(t6[k]) + bf2f(t7[k])));
        c4 = nc4; d4 = nd4; i = ni; have8 = nhave;
    }
    if (i < ep) {                            // tail packet of 4
        int4 e4 = *(const int4*)(cidx + start + i);
        u16x8 t0 = *(const u16x8*)(T2 + (size_t)e4.x * 64 + s * 8);
        u16x8 t1 = *(const u16x8*)(T2 + (size_t)e4.y * 64 + s * 8);
        u16x8 t2 = *(const u16x8*)(T2 + (size_t)e4.z * 64 + s * 8);
        u16x8 t3 = *(const u16x8*)(T2 + (size_t)e4.w * 64 + s * 8);
        #pragma unroll
        for (int k = 0; k < 8; k++)
            a[k] += (bf2f(t0[k]) + bf2f(t1[k])) + (bf2f(t2[k]) + bf2f(t3[k]));
    }

    // epilogue params loaded after the gather loop (short live range)
    float4 ps0 = *(const float4*)(pp + s * 8);
    float4 ps1 = *(const float4*)(pp + s * 8 + 4);
    float4 ph0 = *(const float4*)(pp + 64 + s * 8);
    float4 ph1 = *(const float4*)(pp + 64 + s * 8 + 4);
    float PS[8] = {ps0.x, ps0.y, ps0.z, ps0.w, ps1.x, ps1.y, ps1.z, ps1.w};
    float PH[8] = {ph0.x, ph0.y, ph0.z, ph0.w, ph1.x, ph1.y, ph1.z, ph1.w};

    float v[8];
    #pragma unroll
    for (int k = 0; k < 8; k++) v[k] = 0.f;
    if (rv) {
        #pragma unroll
        for (int k = 0; k < 8; k++) {
            v[k] = dr * (a[k] + bf2f(sf[k])) * PS[k] + PH[k];
            if (relu) v[k] = fmaxf(v[k], 0.f);
        }
        if (outf) {
            *(float4*)(outf + (size_t)r * 64 + s * 8) = make_float4(v[0], v[1], v[2], v[3]);
            *(float4*)(outf + (size_t)r * 64 + s * 8 + 4) = make_float4(v[4], v[5], v[6], v[7]);
        }
    }

    if constexpr (FUSE) {
        // stage activation tile (bf16) into LDS
        u16x8 hv;
        #pragma unroll
        for (int k = 0; k < 8; k++) hv[k] = rv ? f2bf(v[k]) : (ushort)0;
        *(u16x8*)&lds_h[loc][s * 8] = hv;

        // prepacked Wn fragments: one 16B load each
        int m = lane & 15, quad = lane >> 4;
        int rtile = wl >> 1, chalf = wl & 1;   // wave -> (16-row tile, 32-col half)
        bfrag8 bw[2][2];
        #pragma unroll
        for (int ks = 0; ks < 2; ks++)
            #pragma unroll
            for (int c = 0; c < 2; c++)
                bw[ks][c] = *(const bfrag8*)(wq +
                    (size_t)(((((chalf * 2 + c) * 2 + ks) * 4 + quad) * 16 + m) * 8));
        __syncthreads();

        bfrag8 a0 = *(const bfrag8*)&lds_h[rtile * 16 + m][quad * 8];
        bfrag8 a1 = *(const bfrag8*)&lds_h[rtile * 16 + m][32 + quad * 8];
        facc4 acc[2];
        #pragma unroll
        for (int c = 0; c < 2; c++) { acc[c][0]=0.f; acc[c][1]=0.f; acc[c][2]=0.f; acc[c][3]=0.f; }
        #pragma unroll
        for (int c = 0; c < 2; c++) {
            acc[c] = __builtin_amdgcn_mfma_f32_16x16x32_bf16(a0, bw[0][c], acc[c], 0, 0, 0);
            acc[c] = __builtin_amdgcn_mfma_f32_16x16x32_bf16(a1, bw[1][c], acc[c], 0, 0, 0);
        }
        int nodeBase = blockIdx.x * 32 + rtile * 16;
        #pragma unroll
        for (int c = 0; c < 2; c++)
            #pragma unroll
            for (int rr = 0; rr < 4; rr++) {
                int node = nodeBase + quad * 4 + rr;
                if (node < N)
                    Tn[(size_t)node * 64 + (chalf * 2 + c) * 16 + m] =
                        f2bf(dinv[node] * acc[c][rr]);
            }
    }
}

// ---------------- launcher ----------------

extern "C" void kernel_launch(void* const* d_in, const int* in_sizes, int n_in,
                              void* d_out, int out_size, void* d_ws, size_t ws_size,
                              hipStream_t stream) {
    const float* x  = (const float*)d_in[0];
    const int*   ei = (const int*)d_in[1];
    const float *W1 = (const float*)d_in[2],  *b1 = (const float*)d_in[3];
    const float *g1 = (const float*)d_in[4],  *be1= (const float*)d_in[5];
    const float *m1 = (const float*)d_in[6],  *v1 = (const float*)d_in[7];
    const float *W2 = (const float*)d_in[8],  *b2 = (const float*)d_in[9];
    const float *g2 = (const float*)d_in[10], *be2= (const float*)d_in[11];
    const float *m2 = (const float*)d_in[12], *v2 = (const float*)d_in[13];
    const float *W3 = (const float*)d_in[14], *b3 = (const float*)d_in[15];

    int N = in_sizes[0] / 64;
    int E = in_sizes[1] / 2;
    const int* row = ei;
    const int* col = ei + E;
    int ncb = (N + CROWS - 1) / CROWS;

    char* p = (char*)d_ws;
    auto take = [&](size_t b) -> char* {
        char* q = p;
        p += (b + 255) & ~(size_t)255;
        return q;
    };
    int*    ccur  = (int*)   take((size_t)ncb * 4);
    int*    rptr  = (int*)   take((size_t)N * 4);
    int*    deg   = (int*)   take((size_t)N * 4);
    float*  dinv  = (float*) take((size_t)N * 4);
    ushort* wp    = (ushort*)take((size_t)3 * 4096 * 2);
    float*  pp    = (float*) take((size_t)3 * 128 * 4);
    int*    bkt   = (int*)   take((size_t)ncb * CAP * 4);
    int*    cidx  = (int*)   take((size_t)ncb * BPITCH * 4 + 1024);
    ushort* ta    = (ushort*)take((size_t)(N + 1) * 64 * 2);   // +1 sentinel row
    ushort* tb    = (ushort*)take((size_t)(N + 1) * 64 * 2);   // double buffer

    const int TB = 256;
    const int TBP = 1024;                      // wide blocks for latency-bound preprocessing
    int nchunks = (E + CHUNK - 1) / CHUNK;
    k_prep <<<4, TB, 0, stream>>>(W1, W2, W3, b1, g1, be1, m1, v1,
                                  b2, g2, be2, m2, v2, b3, wp, pp,
                                  ccur, ncb, ta, tb, N);
    k_part <<<nchunks, TBP, 0, stream>>>(row, col, E, ccur, bkt, ncb);
    k_build<<<ncb, TBP, 0, stream>>>(bkt, ccur, rptr, deg, dinv, cidx, N);

    float* outp = (float*)d_out;   // [0, N*64): embeddings fp32; [N*64, 2N*64): preds
    int ntiles = (N + 15) >> 4;
    int GG = (ntiles + 3) / 4;                 // 1 tile per wave
    int GA = (N + 31) / 32;                    // 32 rows per block

    // layer 1 GEMM (fp32 x input) -> ta
    k_gemm<<<GG, TB, 0, stream>>>(x, wp, dinv, ta, ntiles, N);
    // layer 1 agg + fused GEMM W2 -> tb
    k_aggf<true><<<GA, TB, 0, stream>>>(ta, rptr, deg, dinv, cidx, pp, 1,
                                        wp + 4096, (float*)nullptr, tb, N);
    // layer 2 agg (embeddings fp32 out) + fused GEMM W3 -> ta
    k_aggf<true><<<GA, TB, 0, stream>>>(tb, rptr, deg, dinv, cidx, pp + 128, 1,
                                        wp + 8192, outp, ta, N);
    // layer 3 agg -> predictions
    k_aggf<false><<<GA, TB, 0, stream>>>(ta, rptr, deg, dinv, cidx, pp + 256, 0,
                                         (const ushort*)nullptr,
                                         outp + (size_t)N * 64, (ushort*)nullptr, N);
}